// Round 1
// baseline (167.277 us; speedup 1.0000x reference)
//
#include <hip/hip_runtime.h>
#include <hip/hip_cooperative_groups.h>

namespace cg = cooperative_groups;

#define N_OPS   60
#define BATCH   256
#define BOXD    12
#define SYMDIM  8
#define NBOX    32
#define NSYM    16
#define FD      1024
#define HD      2048
#define MAXSTK  20
#define MAXSYM  4
#define DZERO   (-1000000)
#define NBLK    64
#define NTHR    256

// Scratch in device globals: every slot read in a call is written earlier in
// the same call (boxes: always; g_h: per stage; g_step[t]: only live t, which
// are exactly the ones written). Deterministic, graph-capture safe.
__device__ float g_boxes[NBOX * FD];
__device__ float g_h[HD];
__device__ float g_step[N_OPS * FD];

struct Params {
  const float* inputStacks;     // [32][256][12]
  const float* symmetryStacks;  // [16][256][8]
  const int*   ops;             // [60][256]
  const float* box_W;  const float* box_b;
  const float* adj_Wl; const float* adj_bl; const float* adj_Wr;
  const float* adj_W2; const float* adj_b2;
  const float* sym_Wl; const float* sym_bl; const float* sym_Wr; const float* sym_br;
  const float* sym_W2; const float* sym_b2;
  float* out;                   // [1024] fp32
};

static __device__ __forceinline__ int clampi(int v, int lo, int hi) {
  return v < lo ? lo : (v > hi ? hi : v);
}

__global__ __launch_bounds__(NTHR) void grass_kernel(Params p) {
  __shared__ int s_type[N_OPS];
  __shared__ int s_a[N_OPS];            // sec desc (adj)
  __shared__ int s_b[N_OPS];            // top desc (adj & sym)
  __shared__ int s_c[N_OPS];            // stop desc (sym): sym-stack row or -1
  __shared__ unsigned char s_live[N_OPS];
  __shared__ int s_root;
  __shared__ float red[NTHR];
  __shared__ float s_x[2 * FD];         // staged input vectors (x / [sec|top] / h)

  const int tid = threadIdx.x, blk = blockIdx.x, nblk = gridDim.x;
  cg::grid_group grid = cg::this_grid();

  // ---- Phase 0: scalar stack-machine simulation + liveness (per-block, redundant)
  if (tid == 0) {
    int sd[MAXSTK], yd[MAXSYM];
    for (int i = 0; i < MAXSTK; ++i) sd[i] = DZERO;
    sd[0] = sd[1] = -1;                 // boxes_enc[0] == desc -(0+1)
    yd[0] = yd[1] = 0;                  // symmetryStacks row 0
    yd[2] = yd[3] = -1;                 // zero vector
    int sptr = 2, yptr = 2, bptr = NBOX - 1, qptr = NSYM - 1;
    for (int t = 0; t < N_OPS; ++t) {
      int op = p.ops[t * BATCH];        // batch 0
      bool push = (op <= 1), madj = (op == 2), psym = (op == 1), msym = (op == 3);
      int pvd  = -(clampi(bptr, 0, NBOX - 1) + 1);
      int svd  = clampi(qptr, 0, NSYM - 1);
      int topd = sd[clampi(sptr - 1, 0, MAXSTK - 1)];
      int secd = sd[clampi(sptr - 2, 0, MAXSTK - 1)];
      int stpd = yd[clampi(yptr - 1, 0, MAXSYM - 1)];
      int wvd, wi, ty;
      if (push)      { wvd = pvd; wi = sptr;     ty = 0; }
      else if (madj) { wvd = t;   wi = sptr - 2; ty = 2; }
      else           { wvd = t;   wi = sptr - 1; ty = 3; }  // wv==sym for any non-push, non-madj op
      s_type[t] = ty; s_a[t] = secd; s_b[t] = topd; s_c[t] = stpd; s_live[t] = 0;
      if (wi >= 0 && wi < MAXSTK) sd[wi] = wvd;  // scatter: OOB dropped
      if (psym) yd[clampi(yptr, 0, MAXSYM - 1)] = svd;
      sptr += push ? 1 : (madj ? -1 : 0);
      yptr += (psym ? 1 : 0) - (msym ? 1 : 0);
      bptr -= push ? 1 : 0;
      qptr -= psym ? 1 : 0;
    }
    int root = sd[clampi(sptr - 1, 0, MAXSTK - 1)];
    s_root = root;
    if (root >= 0) s_live[root] = 1;
    for (int t = N_OPS - 1; t >= 0; --t) {
      if (!s_live[t]) continue;
      if (s_type[t] == 2) {
        if (s_a[t] >= 0) s_live[s_a[t]] = 1;
        if (s_b[t] >= 0) s_live[s_b[t]] = 1;
      } else {
        if (s_b[t] >= 0) s_live[s_b[t]] = 1;
      }
    }
  }
  __syncthreads();

  // ---- Phase 1: boxes_enc for batch 0: [32][1024]
  for (int g = blk * NTHR + tid; g < NBOX * FD; g += nblk * NTHR) {
    int n = g >> 10, f = g & (FD - 1);
    const float* x = p.inputStacks + (size_t)n * (BATCH * BOXD);  // batch 0
    float acc = p.box_b[f];
    #pragma unroll
    for (int d = 0; d < BOXD; ++d) acc += x[d] * p.box_W[d * FD + f];
    g_boxes[g] = tanhf(acc);
  }
  __threadfence();
  grid.sync();

  const int jj = tid & 31, isl = tid >> 5;   // 32 cols x 8 i-slices

  // ---- Phase 2: execute live steps
  for (int t = 0; t < N_OPS; ++t) {
    if (!s_live[t]) continue;
    const int ty = s_type[t];
    const float *xa = nullptr, *xb = nullptr, *stop = nullptr;
    const float *Wl, *Wr = nullptr, *bl, *br = nullptr, *W2, *b2;
    if (ty == 2) {
      int a = s_a[t], b = s_b[t];
      xa = (a == DZERO) ? nullptr : ((a < 0) ? g_boxes + (size_t)(-a - 1) * FD : g_step + (size_t)a * FD);
      xb = (b == DZERO) ? nullptr : ((b < 0) ? g_boxes + (size_t)(-b - 1) * FD : g_step + (size_t)b * FD);
      Wl = p.adj_Wl; Wr = p.adj_Wr; bl = p.adj_bl; W2 = p.adj_W2; b2 = p.adj_b2;
    } else {
      int b = s_b[t], c = s_c[t];
      xa = (b == DZERO) ? nullptr : ((b < 0) ? g_boxes + (size_t)(-b - 1) * FD : g_step + (size_t)b * FD);
      stop = (c < 0) ? nullptr : p.symmetryStacks + (size_t)c * (BATCH * SYMDIM);  // batch 0 row
      Wl = p.sym_Wl; bl = p.sym_bl; br = p.sym_br; W2 = p.sym_W2; b2 = p.sym_b2;
    }

    // L1: h[2048] = tanh(xa@Wl (+ xb@Wr) (+ stop@sym_Wr) + bl (+ br))
    for (int col0 = blk * 32; col0 < HD; col0 += nblk * 32) {
      const int col = col0 + jj;
      // stage input vectors into LDS
      for (int i = tid; i < FD; i += NTHR) s_x[i] = xa ? xa[i] : 0.0f;
      if (ty == 2) for (int i = tid; i < FD; i += NTHR) s_x[FD + i] = xb ? xb[i] : 0.0f;
      __syncthreads();
      float acc = 0.0f;
      const int i0 = isl * (FD / 8);
      if (ty == 2) {
        #pragma unroll 8
        for (int ii = 0; ii < FD / 8; ++ii) {
          int i = i0 + ii;
          acc += s_x[i] * Wl[i * HD + col] + s_x[FD + i] * Wr[i * HD + col];
        }
      } else {
        #pragma unroll 8
        for (int ii = 0; ii < FD / 8; ++ii) {
          int i = i0 + ii;
          acc += s_x[i] * Wl[i * HD + col];
        }
      }
      red[tid] = acc;
      __syncthreads();
      if (isl == 0) {
        float s2 = bl[col];
        #pragma unroll
        for (int k = 0; k < 8; ++k) s2 += red[k * 32 + jj];
        if (ty == 3) {
          s2 += br[col];
          if (stop) {
            #pragma unroll
            for (int k = 0; k < SYMDIM; ++k) s2 += stop[k] * p.sym_Wr[k * HD + col];
          }
        }
        g_h[col] = tanhf(s2);
      }
      __syncthreads();
    }
    __threadfence();
    grid.sync();

    // L2: out[1024] = tanh(h@W2 + b2) -> g_step[t]
    for (int col0 = blk * 32; col0 < FD; col0 += nblk * 32) {
      const int col = col0 + jj;
      for (int i = tid; i < HD; i += NTHR) s_x[i] = g_h[i];
      __syncthreads();
      float acc = 0.0f;
      const int i0 = isl * (HD / 8);
      #pragma unroll 8
      for (int ii = 0; ii < HD / 8; ++ii) {
        int i = i0 + ii;
        acc += s_x[i] * W2[i * FD + col];
      }
      red[tid] = acc;
      __syncthreads();
      if (isl == 0) {
        float s2 = b2[col];
        #pragma unroll
        for (int k = 0; k < 8; ++k) s2 += red[k * 32 + jj];
        g_step[(size_t)t * FD + col] = tanhf(s2);
      }
      __syncthreads();
    }
    __threadfence();
    grid.sync();
  }

  // ---- Phase 3: write root vector
  if (blk == 0) {
    int r = s_root;
    const float* v = (r == DZERO) ? nullptr
                   : ((r < 0) ? g_boxes + (size_t)(-r - 1) * FD : g_step + (size_t)r * FD);
    for (int f = tid; f < FD; f += NTHR) p.out[f] = v ? v[f] : 0.0f;
  }
}

extern "C" void kernel_launch(void* const* d_in, const int* in_sizes, int n_in,
                              void* d_out, int out_size, void* d_ws, size_t ws_size,
                              hipStream_t stream) {
  Params p;
  p.inputStacks    = (const float*)d_in[0];
  p.symmetryStacks = (const float*)d_in[1];
  p.ops            = (const int*)d_in[2];
  p.box_W  = (const float*)d_in[3];
  p.box_b  = (const float*)d_in[4];
  p.adj_Wl = (const float*)d_in[5];
  p.adj_bl = (const float*)d_in[6];
  p.adj_Wr = (const float*)d_in[7];
  p.adj_W2 = (const float*)d_in[8];
  p.adj_b2 = (const float*)d_in[9];
  p.sym_Wl = (const float*)d_in[10];
  p.sym_bl = (const float*)d_in[11];
  p.sym_Wr = (const float*)d_in[12];
  p.sym_br = (const float*)d_in[13];
  p.sym_W2 = (const float*)d_in[14];
  p.sym_b2 = (const float*)d_in[15];
  p.out    = (float*)d_out;

  void* args[] = { &p };
  (void)hipLaunchCooperativeKernel((const void*)grass_kernel,
                                   dim3(NBLK), dim3(NTHR), args, 0, stream);
}